// Round 7
// baseline (1585.281 us; speedup 1.0000x reference)
//
#include <hip/hip_runtime.h>
#include <hip/hip_bf16.h>
#include <stdint.h>

#define S_LEN 4096
#define HN    32
#define SSD   64
#define KD    2048      // D_IN = H*SS = D_OUT
#define MROWS 16384     // B*S

typedef __attribute__((ext_vector_type(4))) float f32x4;
typedef __attribute__((ext_vector_type(8))) short bf16x8;
typedef __attribute__((address_space(3))) char as3char;
typedef __attribute__((address_space(1))) char as1char;

__device__ __forceinline__ unsigned short f2bf(float f){
  unsigned int u = __float_as_uint(f);
  u += 0x7FFFu + ((u >> 16) & 1u);   // round-to-nearest-even
  return (unsigned short)(u >> 16);
}

// ---------------- convert f32 -> bf16 (vectorized, 4 elts/thread) ----------------
__global__ __launch_bounds__(256) void cvt_bf16_k(const float* __restrict__ src,
                                                  unsigned short* __restrict__ dst){
  int i = (blockIdx.x * 256 + threadIdx.x) * 4;
  float4 v = *(const float4*)(src + i);
  ushort4 r;
  r.x = f2bf(v.x); r.y = f2bf(v.y); r.z = f2bf(v.z); r.w = f2bf(v.w);
  *(ushort4*)(dst + i) = r;
}

// ---------------- GEMM (bf16, global_load_lds), optional bias epilogue ----------------
// C[row][col] = sum_k A[row][k]*B[col][k]  (+ bias[col] if bias != nullptr)
__global__ __launch_bounds__(256) void gemm_bf16_k(const unsigned short* __restrict__ A,
                                                   const unsigned short* __restrict__ Bw,
                                                   const float* __restrict__ bias,  // may be null
                                                   float* __restrict__ C){
  __shared__ short As[128*32];
  __shared__ short Bs[128*32];
  const int tid  = threadIdx.x;
  const int bn   = blockIdx.x & 15;
  const int bm   = blockIdx.x >> 4;
  const int lane = tid & 63;
  const int wv   = tid >> 6;
  const int wvU  = __builtin_amdgcn_readfirstlane(wv);
  const int wm   = (wv >> 1) * 64;
  const int wn   = (wv & 1) * 64;

  f32x4 acc[4][4];
#pragma unroll
  for (int i=0;i<4;i++)
#pragma unroll
    for (int j=0;j<4;j++)
#pragma unroll
      for (int q=0;q<4;q++) acc[i][j][q] = 0.0f;

  as3char* asB = (as3char*)As;
  as3char* bsB = (as3char*)Bs;
  as1char* aG  = (as1char*)A;
  as1char* bG  = (as1char*)Bw;

  const int fr  = lane & 15;
  const int fko = (lane >> 4) * 8;

  for (int kt=0; kt<KD/32; ++kt){
    __syncthreads();                 // previous tile's frag reads done
#pragma unroll
    for (int c=0;c<2;c++){
      const int off  = (wvU*2 + c)*1024 + lane*16;
      const int row  = off >> 6;
      const int colB = off & 63;
      __builtin_amdgcn_global_load_lds(
        (__attribute__((address_space(1))) void*)(aG + (size_t)(bm*128 + row)*4096 + (size_t)kt*64 + colB),
        (__attribute__((address_space(3))) void*)(asB + (wvU*2 + c)*1024),
        16, 0, 0);
      __builtin_amdgcn_global_load_lds(
        (__attribute__((address_space(1))) void*)(bG + (size_t)(bn*128 + row)*4096 + (size_t)kt*64 + colB),
        (__attribute__((address_space(3))) void*)(bsB + (wvU*2 + c)*1024),
        16, 0, 0);
    }
    __syncthreads();                 // loads landed (vmcnt drain at barrier)

    bf16x8 af[4], bq[4];
#pragma unroll
    for (int mt=0; mt<4; mt++) af[mt] = *(const bf16x8*)&As[(wm + mt*16 + fr)*32 + fko];
#pragma unroll
    for (int nt=0; nt<4; nt++) bq[nt] = *(const bf16x8*)&Bs[(wn + nt*16 + fr)*32 + fko];
#pragma unroll
    for (int mt=0; mt<4; mt++)
#pragma unroll
      for (int nt=0; nt<4; nt++)
        acc[mt][nt] = __builtin_amdgcn_mfma_f32_16x16x32_bf16(af[mt], bq[nt], acc[mt][nt], 0, 0, 0);
  }

  float bv[4] = {0.f, 0.f, 0.f, 0.f};
  if (bias){
#pragma unroll
    for (int nt=0; nt<4; nt++) bv[nt] = bias[bn*128 + wn + nt*16 + fr];
  }
#pragma unroll
  for (int mt=0; mt<4; mt++)
#pragma unroll
    for (int nt=0; nt<4; nt++){
      const int col = bn*128 + wn + nt*16 + fr;
#pragma unroll
      for (int q=0; q<4; q++){
        const int row = bm*128 + wm + mt*16 + (lane>>4)*4 + q;
        C[(size_t)row*KD + col] = acc[mt][nt][q] + bv[nt];
      }
    }
}

// ---------------- scan: y_t = tanh(W_h y_{t-1} + hx_t) ----------------
// Register-resident: ONE wave per (b,h) chain; lane o owns y[o] and W row o.
// Weights held as 16 NAMED f32x4 SSA values (no array, no type-punning):
// R5/R6 showed `float w[64]` + float4-punned fill defeats SROA -> scratch
// reloads every step (VGPR_Count=48). Named vectors cannot be demoted.
// Broadcast of y[j] is v_readlane (compile-time lane) -> SGPR into v_fmac.
// Zero LDS, zero barriers; hx prefetch 8-deep and ybf stores stay in flight.
__global__ __launch_bounds__(64, 1) void scan_k(const float* __restrict__ hx,
                                                const float* __restrict__ sw,   // [32][64][64]
                                                const float* __restrict__ st0,  // [4][32][64]
                                                unsigned short* __restrict__ ybf){ // [MROWS][2048] bf16
  const int b = blockIdx.x >> 5, h = blockIdx.x & 31;
  const int lane = threadIdx.x;        // = output index o
  const f32x4* wv = (const f32x4*)(sw + ((size_t)(h*64 + lane))*64);
  f32x4 w0  = wv[0],  w1  = wv[1],  w2  = wv[2],  w3  = wv[3],
        w4  = wv[4],  w5  = wv[5],  w6  = wv[6],  w7  = wv[7],
        w8  = wv[8],  w9  = wv[9],  w10 = wv[10], w11 = wv[11],
        w12 = wv[12], w13 = wv[13], w14 = wv[14], w15 = wv[15];

  float y = st0[(b*32 + h)*64 + lane];
  const float* hxp = hx + (size_t)b*S_LEN*KD + h*64 + lane;
  const size_t yo  = (size_t)b*S_LEN*KD + h*64 + lane;

  float hpre[8];
#pragma unroll
  for (int i=0;i<8;i++) hpre[i] = hxp[(size_t)i*KD];

#pragma unroll 8
  for (int t=0; t<S_LEN; ++t){
    const float hxv = hpre[t & 7];
    const int tn = (t + 8 < S_LEN) ? (t + 8) : (S_LEN - 1);
    hpre[t & 7] = hxp[(size_t)tn*KD];

    const int yi = __float_as_int(y);
    float a0=0.f, a1=0.f, a2=0.f, a3=0.f;
#define FMA4(W, J) \
    a0 = fmaf(W[0], __int_as_float(__builtin_amdgcn_readlane(yi, (J)+0)), a0); \
    a1 = fmaf(W[1], __int_as_float(__builtin_amdgcn_readlane(yi, (J)+1)), a1); \
    a2 = fmaf(W[2], __int_as_float(__builtin_amdgcn_readlane(yi, (J)+2)), a2); \
    a3 = fmaf(W[3], __int_as_float(__builtin_amdgcn_readlane(yi, (J)+3)), a3);
    FMA4(w0,  0)  FMA4(w1,  4)  FMA4(w2,  8)  FMA4(w3,  12)
    FMA4(w4,  16) FMA4(w5,  20) FMA4(w6,  24) FMA4(w7,  28)
    FMA4(w8,  32) FMA4(w9,  36) FMA4(w10, 40) FMA4(w11, 44)
    FMA4(w12, 48) FMA4(w13, 52) FMA4(w14, 56) FMA4(w15, 60)
#undef FMA4
    const float u = (a0 + a1) + (a2 + a3) + hxv;
    const float e = __expf(2.0f*u);
    y = 1.0f - 2.0f*__builtin_amdgcn_rcpf(e + 1.0f);   // tanh(u)
    ybf[yo + (size_t)t*KD] = f2bf(y);
  }
}

extern "C" void kernel_launch(void* const* d_in, const int* in_sizes, int n_in,
                              void* d_out, int out_size, void* d_ws, size_t ws_size,
                              hipStream_t stream) {
  const float* x      = (const float*)d_in[0];
  const float* st0    = (const float*)d_in[1];
  const float* w_in   = (const float*)d_in[2];
  const float* w_st   = (const float*)d_in[3];
  const float* b_st   = (const float*)d_in[4];
  const float* w_out  = (const float*)d_in[5];
  float* out = (float*)d_out;

  // workspace layout (209 MiB total, regions time-shared):
  //   [0,            HX_B)        hx f32 (134MB)
  //   [HX_B,         HX_B+Y_B)    phase1: x_bf16 (67MB); phase2: y_bf16 (scan overwrites)
  //   [HX_B+Y_B,     +WO_B)       phase1: w_in_bf16 (8MB); phase2: w_out_bf16
  const size_t HX_B = (size_t)MROWS * KD * 4;       // 134217728
  const size_t Y_B  = (size_t)MROWS * KD * 2;       // 67108864
  const size_t WO_B = (size_t)KD * KD * 2;          // 8388608
  if (ws_size < HX_B + Y_B + WO_B) return;          // fail loudly rather than corrupt
  char* ws = (char*)d_ws;
  float*          hx   = (float*)ws;
  unsigned short* ybf  = (unsigned short*)(ws + HX_B);   // doubles as x_bf16
  unsigned short* wbf  = (unsigned short*)(ws + HX_B + Y_B); // w_in then w_out

  // phase 1: convert x and w_in, input GEMM (+bias)
  cvt_bf16_k<<<dim3((MROWS*(size_t)KD)/1024), dim3(256), 0, stream>>>(x, ybf);
  cvt_bf16_k<<<dim3((KD*KD)/1024), dim3(256), 0, stream>>>(w_in, wbf);
  gemm_bf16_k<<<dim3((MROWS/128)*(KD/128)), dim3(256), 0, stream>>>(ybf, wbf, b_st, hx);
  // phase 2: scan (overwrites x_bf16 region with y), then output GEMM
  scan_k<<<dim3(128), dim3(64), 0, stream>>>(hx, w_st, st0, ybf);
  cvt_bf16_k<<<dim3((KD*KD)/1024), dim3(256), 0, stream>>>(w_out, wbf);
  gemm_bf16_k<<<dim3((MROWS/128)*(KD/128)), dim3(256), 0, stream>>>(ybf, wbf, nullptr, out);
}

// Round 8
// 1573.602 us; speedup vs baseline: 1.0074x; 1.0074x over previous
//
#include <hip/hip_runtime.h>
#include <hip/hip_bf16.h>
#include <stdint.h>

#define S_LEN 4096
#define HN    32
#define SSD   64
#define KD    2048      // D_IN = H*SS = D_OUT
#define MROWS 16384     // B*S

typedef __attribute__((ext_vector_type(4))) float f32x4;
typedef __attribute__((ext_vector_type(8))) short bf16x8;
typedef __attribute__((address_space(3))) char as3char;
typedef __attribute__((address_space(1))) char as1char;

__device__ __forceinline__ unsigned short f2bf(float f){
  unsigned int u = __float_as_uint(f);
  u += 0x7FFFu + ((u >> 16) & 1u);   // round-to-nearest-even
  return (unsigned short)(u >> 16);
}

// ---------------- convert f32 -> bf16 (vectorized, 4 elts/thread) ----------------
__global__ __launch_bounds__(256) void cvt_bf16_k(const float* __restrict__ src,
                                                  unsigned short* __restrict__ dst){
  int i = (blockIdx.x * 256 + threadIdx.x) * 4;
  float4 v = *(const float4*)(src + i);
  ushort4 r;
  r.x = f2bf(v.x); r.y = f2bf(v.y); r.z = f2bf(v.z); r.w = f2bf(v.w);
  *(ushort4*)(dst + i) = r;
}

// ---------------- GEMM (bf16, global_load_lds), optional bias epilogue ----------------
// C[row][col] = sum_k A[row][k]*B[col][k]  (+ bias[col] if bias != nullptr)
__global__ __launch_bounds__(256) void gemm_bf16_k(const unsigned short* __restrict__ A,
                                                   const unsigned short* __restrict__ Bw,
                                                   const float* __restrict__ bias,  // may be null
                                                   float* __restrict__ C){
  __shared__ short As[128*32];
  __shared__ short Bs[128*32];
  const int tid  = threadIdx.x;
  const int bn   = blockIdx.x & 15;
  const int bm   = blockIdx.x >> 4;
  const int lane = tid & 63;
  const int wv   = tid >> 6;
  const int wvU  = __builtin_amdgcn_readfirstlane(wv);
  const int wm   = (wv >> 1) * 64;
  const int wn   = (wv & 1) * 64;

  f32x4 acc[4][4];
#pragma unroll
  for (int i=0;i<4;i++)
#pragma unroll
    for (int j=0;j<4;j++)
#pragma unroll
      for (int q=0;q<4;q++) acc[i][j][q] = 0.0f;

  as3char* asB = (as3char*)As;
  as3char* bsB = (as3char*)Bs;
  as1char* aG  = (as1char*)A;
  as1char* bG  = (as1char*)Bw;

  const int fr  = lane & 15;
  const int fko = (lane >> 4) * 8;

  for (int kt=0; kt<KD/32; ++kt){
    __syncthreads();                 // previous tile's frag reads done
#pragma unroll
    for (int c=0;c<2;c++){
      const int off  = (wvU*2 + c)*1024 + lane*16;
      const int row  = off >> 6;
      const int colB = off & 63;
      __builtin_amdgcn_global_load_lds(
        (__attribute__((address_space(1))) void*)(aG + (size_t)(bm*128 + row)*4096 + (size_t)kt*64 + colB),
        (__attribute__((address_space(3))) void*)(asB + (wvU*2 + c)*1024),
        16, 0, 0);
      __builtin_amdgcn_global_load_lds(
        (__attribute__((address_space(1))) void*)(bG + (size_t)(bn*128 + row)*4096 + (size_t)kt*64 + colB),
        (__attribute__((address_space(3))) void*)(bsB + (wvU*2 + c)*1024),
        16, 0, 0);
    }
    __syncthreads();                 // loads landed (vmcnt drain at barrier)

    bf16x8 af[4], bq[4];
#pragma unroll
    for (int mt=0; mt<4; mt++) af[mt] = *(const bf16x8*)&As[(wm + mt*16 + fr)*32 + fko];
#pragma unroll
    for (int nt=0; nt<4; nt++) bq[nt] = *(const bf16x8*)&Bs[(wn + nt*16 + fr)*32 + fko];
#pragma unroll
    for (int mt=0; mt<4; mt++)
#pragma unroll
      for (int nt=0; nt<4; nt++)
        acc[mt][nt] = __builtin_amdgcn_mfma_f32_16x16x32_bf16(af[mt], bq[nt], acc[mt][nt], 0, 0, 0);
  }

  float bv[4] = {0.f, 0.f, 0.f, 0.f};
  if (bias){
#pragma unroll
    for (int nt=0; nt<4; nt++) bv[nt] = bias[bn*128 + wn + nt*16 + fr];
  }
#pragma unroll
  for (int mt=0; mt<4; mt++)
#pragma unroll
    for (int nt=0; nt<4; nt++){
      const int col = bn*128 + wn + nt*16 + fr;
#pragma unroll
      for (int q=0; q<4; q++){
        const int row = bm*128 + wm + mt*16 + (lane>>4)*4 + q;
        C[(size_t)row*KD + col] = acc[mt][nt][q] + bv[nt];
      }
    }
}

// ---------------- scan: y_t = tanh(W_h y_{t-1} + hx_t) ----------------
// Register-resident: ONE wave per (b,h) chain; lane o owns y[o] and W row o.
// R5-R7 failure mode: the GCN scheduler's occupancy-targeting remat stage
// sank the loop-invariant weight loads INTO the loop (VGPR_Count pinned at
// 48, identical codegen for array / launch_bounds(64,1) / named-SSA forms).
// Two levers against that mechanism:
//   (a) amdgpu_waves_per_eu(1,1): occupancy target = 1 wave/EU (correct for
//       this dispatch: 128 single-wave blocks on 256 CUs) -> no motive.
//   (b) asm-pin the 16 f32x4 weight values: asm output is not
//       rematerializable -> no means.
// Broadcast of y[j] is v_readlane (compile-time lane) -> SGPR into v_fmac.
// Zero LDS, zero barriers; hx prefetch 8-deep and ybf stores stay in flight.
__global__ __attribute__((amdgpu_flat_work_group_size(64, 64)))
__attribute__((amdgpu_waves_per_eu(1, 1)))
void scan_k(const float* __restrict__ hx,
            const float* __restrict__ sw,   // [32][64][64]
            const float* __restrict__ st0,  // [4][32][64]
            unsigned short* __restrict__ ybf){ // [MROWS][2048] bf16
  const int b = blockIdx.x >> 5, h = blockIdx.x & 31;
  const int lane = threadIdx.x;        // = output index o
  const f32x4* wv = (const f32x4*)(sw + ((size_t)(h*64 + lane))*64);
  f32x4 w0  = wv[0],  w1  = wv[1],  w2  = wv[2],  w3  = wv[3],
        w4  = wv[4],  w5  = wv[5],  w6  = wv[6],  w7  = wv[7],
        w8  = wv[8],  w9  = wv[9],  w10 = wv[10], w11 = wv[11],
        w12 = wv[12], w13 = wv[13], w14 = wv[14], w15 = wv[15];
  // (b) pin: values become asm-produced -> cannot be rematerialized in-loop.
  asm volatile("" : "+v"(w0), "+v"(w1), "+v"(w2),  "+v"(w3),
                    "+v"(w4), "+v"(w5), "+v"(w6),  "+v"(w7),
                    "+v"(w8), "+v"(w9), "+v"(w10), "+v"(w11),
                    "+v"(w12),"+v"(w13),"+v"(w14), "+v"(w15));

  float y = st0[(b*32 + h)*64 + lane];
  const float* hxp = hx + (size_t)b*S_LEN*KD + h*64 + lane;
  const size_t yo  = (size_t)b*S_LEN*KD + h*64 + lane;

  float hpre[8];
#pragma unroll
  for (int i=0;i<8;i++) hpre[i] = hxp[(size_t)i*KD];

#pragma unroll 8
  for (int t=0; t<S_LEN; ++t){
    const float hxv = hpre[t & 7];
    const int tn = (t + 8 < S_LEN) ? (t + 8) : (S_LEN - 1);
    hpre[t & 7] = hxp[(size_t)tn*KD];

    const int yi = __float_as_int(y);
    float a0=0.f, a1=0.f, a2=0.f, a3=0.f;
#define FMA4(W, J) \
    a0 = fmaf(W[0], __int_as_float(__builtin_amdgcn_readlane(yi, (J)+0)), a0); \
    a1 = fmaf(W[1], __int_as_float(__builtin_amdgcn_readlane(yi, (J)+1)), a1); \
    a2 = fmaf(W[2], __int_as_float(__builtin_amdgcn_readlane(yi, (J)+2)), a2); \
    a3 = fmaf(W[3], __int_as_float(__builtin_amdgcn_readlane(yi, (J)+3)), a3);
    FMA4(w0,  0)  FMA4(w1,  4)  FMA4(w2,  8)  FMA4(w3,  12)
    FMA4(w4,  16) FMA4(w5,  20) FMA4(w6,  24) FMA4(w7,  28)
    FMA4(w8,  32) FMA4(w9,  36) FMA4(w10, 40) FMA4(w11, 44)
    FMA4(w12, 48) FMA4(w13, 52) FMA4(w14, 56) FMA4(w15, 60)
#undef FMA4
    const float u = (a0 + a1) + (a2 + a3) + hxv;
    const float e = __expf(2.0f*u);
    y = 1.0f - 2.0f*__builtin_amdgcn_rcpf(e + 1.0f);   // tanh(u)
    ybf[yo + (size_t)t*KD] = f2bf(y);
  }
}

extern "C" void kernel_launch(void* const* d_in, const int* in_sizes, int n_in,
                              void* d_out, int out_size, void* d_ws, size_t ws_size,
                              hipStream_t stream) {
  const float* x      = (const float*)d_in[0];
  const float* st0    = (const float*)d_in[1];
  const float* w_in   = (const float*)d_in[2];
  const float* w_st   = (const float*)d_in[3];
  const float* b_st   = (const float*)d_in[4];
  const float* w_out  = (const float*)d_in[5];
  float* out = (float*)d_out;

  // workspace layout (209 MiB total, regions time-shared):
  //   [0,            HX_B)        hx f32 (134MB)
  //   [HX_B,         HX_B+Y_B)    phase1: x_bf16 (67MB); phase2: y_bf16 (scan overwrites)
  //   [HX_B+Y_B,     +WO_B)       phase1: w_in_bf16 (8MB); phase2: w_out_bf16
  const size_t HX_B = (size_t)MROWS * KD * 4;       // 134217728
  const size_t Y_B  = (size_t)MROWS * KD * 2;       // 67108864
  const size_t WO_B = (size_t)KD * KD * 2;          // 8388608
  if (ws_size < HX_B + Y_B + WO_B) return;          // fail loudly rather than corrupt
  char* ws = (char*)d_ws;
  float*          hx   = (float*)ws;
  unsigned short* ybf  = (unsigned short*)(ws + HX_B);   // doubles as x_bf16
  unsigned short* wbf  = (unsigned short*)(ws + HX_B + Y_B); // w_in then w_out

  // phase 1: convert x and w_in, input GEMM (+bias)
  cvt_bf16_k<<<dim3((MROWS*(size_t)KD)/1024), dim3(256), 0, stream>>>(x, ybf);
  cvt_bf16_k<<<dim3((KD*KD)/1024), dim3(256), 0, stream>>>(w_in, wbf);
  gemm_bf16_k<<<dim3((MROWS/128)*(KD/128)), dim3(256), 0, stream>>>(ybf, wbf, b_st, hx);
  // phase 2: scan (overwrites x_bf16 region with y), then output GEMM
  scan_k<<<dim3(128), dim3(64), 0, stream>>>(hx, w_st, st0, ybf);
  cvt_bf16_k<<<dim3((KD*KD)/1024), dim3(256), 0, stream>>>(w_out, wbf);
  gemm_bf16_k<<<dim3((MROWS/128)*(KD/128)), dim3(256), 0, stream>>>(ybf, wbf, nullptr, out);
}

// Round 9
// 1553.058 us; speedup vs baseline: 1.0207x; 1.0132x over previous
//
#include <hip/hip_runtime.h>
#include <hip/hip_bf16.h>
#include <stdint.h>

#define S_LEN 4096
#define HN    32
#define SSD   64
#define KD    2048      // D_IN = H*SS = D_OUT
#define MROWS 16384     // B*S

typedef __attribute__((ext_vector_type(4))) float f32x4;
typedef __attribute__((ext_vector_type(8))) short bf16x8;
typedef __attribute__((address_space(3))) char as3char;
typedef __attribute__((address_space(1))) char as1char;

__device__ __forceinline__ unsigned short f2bf(float f){
  unsigned int u = __float_as_uint(f);
  u += 0x7FFFu + ((u >> 16) & 1u);   // round-to-nearest-even
  return (unsigned short)(u >> 16);
}

// ---------------- convert f32 -> bf16 (vectorized, 4 elts/thread) ----------------
__global__ __launch_bounds__(256) void cvt_bf16_k(const float* __restrict__ src,
                                                  unsigned short* __restrict__ dst){
  int i = (blockIdx.x * 256 + threadIdx.x) * 4;
  float4 v = *(const float4*)(src + i);
  ushort4 r;
  r.x = f2bf(v.x); r.y = f2bf(v.y); r.z = f2bf(v.z); r.w = f2bf(v.w);
  *(ushort4*)(dst + i) = r;
}

// ---------------- GEMM (bf16, global_load_lds), optional bias epilogue ----------------
// C[row][col] = sum_k A[row][k]*B[col][k]  (+ bias[col] if bias != nullptr)
__global__ __launch_bounds__(256) void gemm_bf16_k(const unsigned short* __restrict__ A,
                                                   const unsigned short* __restrict__ Bw,
                                                   const float* __restrict__ bias,  // may be null
                                                   float* __restrict__ C){
  __shared__ short As[128*32];
  __shared__ short Bs[128*32];
  const int tid  = threadIdx.x;
  const int bn   = blockIdx.x & 15;
  const int bm   = blockIdx.x >> 4;
  const int lane = tid & 63;
  const int wv   = tid >> 6;
  const int wvU  = __builtin_amdgcn_readfirstlane(wv);
  const int wm   = (wv >> 1) * 64;
  const int wn   = (wv & 1) * 64;

  f32x4 acc[4][4];
#pragma unroll
  for (int i=0;i<4;i++)
#pragma unroll
    for (int j=0;j<4;j++)
#pragma unroll
      for (int q=0;q<4;q++) acc[i][j][q] = 0.0f;

  as3char* asB = (as3char*)As;
  as3char* bsB = (as3char*)Bs;
  as1char* aG  = (as1char*)A;
  as1char* bG  = (as1char*)Bw;

  const int fr  = lane & 15;
  const int fko = (lane >> 4) * 8;

  for (int kt=0; kt<KD/32; ++kt){
    __syncthreads();                 // previous tile's frag reads done
#pragma unroll
    for (int c=0;c<2;c++){
      const int off  = (wvU*2 + c)*1024 + lane*16;
      const int row  = off >> 6;
      const int colB = off & 63;
      __builtin_amdgcn_global_load_lds(
        (__attribute__((address_space(1))) void*)(aG + (size_t)(bm*128 + row)*4096 + (size_t)kt*64 + colB),
        (__attribute__((address_space(3))) void*)(asB + (wvU*2 + c)*1024),
        16, 0, 0);
      __builtin_amdgcn_global_load_lds(
        (__attribute__((address_space(1))) void*)(bG + (size_t)(bn*128 + row)*4096 + (size_t)kt*64 + colB),
        (__attribute__((address_space(3))) void*)(bsB + (wvU*2 + c)*1024),
        16, 0, 0);
    }
    __syncthreads();                 // loads landed (vmcnt drain at barrier)

    bf16x8 af[4], bq[4];
#pragma unroll
    for (int mt=0; mt<4; mt++) af[mt] = *(const bf16x8*)&As[(wm + mt*16 + fr)*32 + fko];
#pragma unroll
    for (int nt=0; nt<4; nt++) bq[nt] = *(const bf16x8*)&Bs[(wn + nt*16 + fr)*32 + fko];
#pragma unroll
    for (int mt=0; mt<4; mt++)
#pragma unroll
      for (int nt=0; nt<4; nt++)
        acc[mt][nt] = __builtin_amdgcn_mfma_f32_16x16x32_bf16(af[mt], bq[nt], acc[mt][nt], 0, 0, 0);
  }

  float bv[4] = {0.f, 0.f, 0.f, 0.f};
  if (bias){
#pragma unroll
    for (int nt=0; nt<4; nt++) bv[nt] = bias[bn*128 + wn + nt*16 + fr];
  }
#pragma unroll
  for (int mt=0; mt<4; mt++)
#pragma unroll
    for (int nt=0; nt<4; nt++){
      const int col = bn*128 + wn + nt*16 + fr;
#pragma unroll
      for (int q=0; q<4; q++){
        const int row = bm*128 + wm + mt*16 + (lane>>4)*4 + q;
        C[(size_t)row*KD + col] = acc[mt][nt][q] + bv[nt];
      }
    }
}

// ---------------- scan: y_t = tanh(W_h y_{t-1} + hx_t) ----------------
// ONE wave per (b,h) chain; lane o owns y[o] and W row o (asm-pinned f32x4
// SSA values; R8 confirmed resident: VGPR 48->132).
// R8's key finding: dur was IDENTICAL across wildly different codegen ->
// loop pinned by serially-exposed hx load latency. Root cause candidate:
// hpre[t&7] runtime-indexed array -> scratch -> prefetch pipeline collapsed
// (each step waits its own global load). Fix: EIGHT NAMED scalar prefetch
// registers h0..h7 rotated by a hand-written 8-step body (macro-expanded;
// no arrays, no dynamic indices anywhere). Load issued at step t for t+8;
// consumed 8 steps later -> 8 loads genuinely in flight.
__global__ __attribute__((amdgpu_flat_work_group_size(64, 64)))
__attribute__((amdgpu_waves_per_eu(1, 1)))
void scan_k(const float* __restrict__ hx,
            const float* __restrict__ sw,   // [32][64][64]
            const float* __restrict__ st0,  // [4][32][64]
            unsigned short* __restrict__ ybf){ // [MROWS][2048] bf16
  const int b = blockIdx.x >> 5, h = blockIdx.x & 31;
  const int lane = threadIdx.x;        // = output index o
  const f32x4* wv = (const f32x4*)(sw + ((size_t)(h*64 + lane))*64);
  f32x4 w0  = wv[0],  w1  = wv[1],  w2  = wv[2],  w3  = wv[3],
        w4  = wv[4],  w5  = wv[5],  w6  = wv[6],  w7  = wv[7],
        w8  = wv[8],  w9  = wv[9],  w10 = wv[10], w11 = wv[11],
        w12 = wv[12], w13 = wv[13], w14 = wv[14], w15 = wv[15];
  // pin: values become asm-produced -> cannot be rematerialized in-loop.
  asm volatile("" : "+v"(w0), "+v"(w1), "+v"(w2),  "+v"(w3),
                    "+v"(w4), "+v"(w5), "+v"(w6),  "+v"(w7),
                    "+v"(w8), "+v"(w9), "+v"(w10), "+v"(w11),
                    "+v"(w12),"+v"(w13),"+v"(w14), "+v"(w15));

  float y = st0[(b*32 + h)*64 + lane];
  const float* hxp = hx + (size_t)b*S_LEN*KD + h*64 + lane;
  const size_t yo  = (size_t)b*S_LEN*KD + h*64 + lane;

  // 8 NAMED prefetch registers (no array -> no scratch, no dynamic index)
  float h0 = hxp[0*(size_t)KD], h1 = hxp[1*(size_t)KD],
        h2 = hxp[2*(size_t)KD], h3 = hxp[3*(size_t)KD],
        h4 = hxp[4*(size_t)KD], h5 = hxp[5*(size_t)KD],
        h6 = hxp[6*(size_t)KD], h7 = hxp[7*(size_t)KD];

#define FMA4(W, J) \
    a0 = fmaf(W[0], __int_as_float(__builtin_amdgcn_readlane(yi, (J)+0)), a0); \
    a1 = fmaf(W[1], __int_as_float(__builtin_amdgcn_readlane(yi, (J)+1)), a1); \
    a2 = fmaf(W[2], __int_as_float(__builtin_amdgcn_readlane(yi, (J)+2)), a2); \
    a3 = fmaf(W[3], __int_as_float(__builtin_amdgcn_readlane(yi, (J)+3)), a3);

#define RNN_STEP(H, TT) { \
    const float hxv = H; \
    { const int tn_ = ((TT) + 8 < S_LEN) ? ((TT) + 8) : (S_LEN - 1); \
      H = hxp[(size_t)tn_ * KD]; } \
    const int yi = __float_as_int(y); \
    float a0=0.f, a1=0.f, a2=0.f, a3=0.f; \
    FMA4(w0,  0)  FMA4(w1,  4)  FMA4(w2,  8)  FMA4(w3,  12) \
    FMA4(w4,  16) FMA4(w5,  20) FMA4(w6,  24) FMA4(w7,  28) \
    FMA4(w8,  32) FMA4(w9,  36) FMA4(w10, 40) FMA4(w11, 44) \
    FMA4(w12, 48) FMA4(w13, 52) FMA4(w14, 56) FMA4(w15, 60) \
    const float u = (a0 + a1) + (a2 + a3) + hxv; \
    const float e = __expf(2.0f*u); \
    y = 1.0f - 2.0f*__builtin_amdgcn_rcpf(e + 1.0f); \
    ybf[yo + (size_t)(TT)*KD] = f2bf(y); }

  for (int t = 0; t < S_LEN; t += 8){
    RNN_STEP(h0, t+0)
    RNN_STEP(h1, t+1)
    RNN_STEP(h2, t+2)
    RNN_STEP(h3, t+3)
    RNN_STEP(h4, t+4)
    RNN_STEP(h5, t+5)
    RNN_STEP(h6, t+6)
    RNN_STEP(h7, t+7)
  }
#undef RNN_STEP
#undef FMA4
}

extern "C" void kernel_launch(void* const* d_in, const int* in_sizes, int n_in,
                              void* d_out, int out_size, void* d_ws, size_t ws_size,
                              hipStream_t stream) {
  const float* x      = (const float*)d_in[0];
  const float* st0    = (const float*)d_in[1];
  const float* w_in   = (const float*)d_in[2];
  const float* w_st   = (const float*)d_in[3];
  const float* b_st   = (const float*)d_in[4];
  const float* w_out  = (const float*)d_in[5];
  float* out = (float*)d_out;

  // workspace layout (209 MiB total, regions time-shared):
  //   [0,            HX_B)        hx f32 (134MB)
  //   [HX_B,         HX_B+Y_B)    phase1: x_bf16 (67MB); phase2: y_bf16 (scan overwrites)
  //   [HX_B+Y_B,     +WO_B)       phase1: w_in_bf16 (8MB); phase2: w_out_bf16
  const size_t HX_B = (size_t)MROWS * KD * 4;       // 134217728
  const size_t Y_B  = (size_t)MROWS * KD * 2;       // 67108864
  const size_t WO_B = (size_t)KD * KD * 2;          // 8388608
  if (ws_size < HX_B + Y_B + WO_B) return;          // fail loudly rather than corrupt
  char* ws = (char*)d_ws;
  float*          hx   = (float*)ws;
  unsigned short* ybf  = (unsigned short*)(ws + HX_B);   // doubles as x_bf16
  unsigned short* wbf  = (unsigned short*)(ws + HX_B + Y_B); // w_in then w_out

  // phase 1: convert x and w_in, input GEMM (+bias)
  cvt_bf16_k<<<dim3((MROWS*(size_t)KD)/1024), dim3(256), 0, stream>>>(x, ybf);
  cvt_bf16_k<<<dim3((KD*KD)/1024), dim3(256), 0, stream>>>(w_in, wbf);
  gemm_bf16_k<<<dim3((MROWS/128)*(KD/128)), dim3(256), 0, stream>>>(ybf, wbf, b_st, hx);
  // phase 2: scan (overwrites x_bf16 region with y), then output GEMM
  scan_k<<<dim3(128), dim3(64), 0, stream>>>(hx, w_st, st0, ybf);
  cvt_bf16_k<<<dim3((KD*KD)/1024), dim3(256), 0, stream>>>(w_out, wbf);
  gemm_bf16_k<<<dim3((MROWS/128)*(KD/128)), dim3(256), 0, stream>>>(ybf, wbf, nullptr, out);
}